// Round 1
// baseline (330.593 us; speedup 1.0000x reference)
//
#include <hip/hip_runtime.h>
#include <math.h>

// Quantize/dequantize with 64-level sorted codebook.
// symbols = argmin_j |codebook[j] - (x - means)|  (tie -> lower index)
// y_hat   = codebook[symbols] + means
//
// Nearest-level via lower_bound over the 63 midpoints between adjacent
// codebook levels: symbol = #{ mid[j] < r }. Tie (r == mid) not counted
// -> picks the LEFT level, matching the reference's (r-left <= right-r).

__global__ __launch_bounds__(256) void quant_dequant_kernel(
    const float4* __restrict__ x4,
    const float4* __restrict__ m4,
    const float*  __restrict__ codebook,
    float4* __restrict__ sym_out,   // symbols as float values
    float4* __restrict__ yhat_out,
    int n4)
{
    __shared__ float s_cb[64];
    __shared__ float s_mid[64];   // 63 midpoints + INF pad

    const int tid = threadIdx.x;
    if (tid < 64) s_cb[tid] = codebook[tid];
    __syncthreads();
    if (tid < 64)
        s_mid[tid] = (tid < 63) ? 0.5f * (s_cb[tid] + s_cb[tid + 1])
                                : INFINITY;
    __syncthreads();

    const int i = blockIdx.x * blockDim.x + tid;
    if (i >= n4) return;

    const float4 xv = x4[i];
    const float4 mv = m4[i];

    float r[4] = { xv.x - mv.x, xv.y - mv.y, xv.z - mv.z, xv.w - mv.w };
    float mm[4] = { mv.x, mv.y, mv.z, mv.w };
    float sym[4], yh[4];

#pragma unroll
    for (int k = 0; k < 4; ++k) {
        // branchless lower_bound over 64-entry array (only first 63 are real;
        // pos+s-1 never reaches index 63). pos = count of mids < r.
        int pos = 0;
#pragma unroll
        for (int s = 32; s > 0; s >>= 1) {
            pos += (s_mid[pos + s - 1] < r[k]) ? s : 0;
        }
        sym[k] = (float)pos;
        yh[k]  = s_cb[pos] + mm[k];
    }

    sym_out[i]  = make_float4(sym[0], sym[1], sym[2], sym[3]);
    yhat_out[i] = make_float4(yh[0], yh[1], yh[2], yh[3]);
}

extern "C" void kernel_launch(void* const* d_in, const int* in_sizes, int n_in,
                              void* d_out, int out_size, void* d_ws, size_t ws_size,
                              hipStream_t stream)
{
    const float* x     = (const float*)d_in[0];
    const float* means = (const float*)d_in[1];
    const float* cb    = (const float*)d_in[2];

    const int n  = in_sizes[0];      // 25,165,824
    const int n4 = n / 4;            // divisible: 6,291,456

    float* out = (float*)d_out;      // [0..n): symbols (as float), [n..2n): y_hat

    const int block = 256;
    const int grid  = (n4 + block - 1) / block;   // 24576

    quant_dequant_kernel<<<grid, block, 0, stream>>>(
        (const float4*)x, (const float4*)means, cb,
        (float4*)out, (float4*)(out + n), n4);
}